// Round 7
// baseline (66.673 us; speedup 1.0000x reference)
//
#include <hip/hip_runtime.h>
#include <math.h>

// GeodesicPrototypeClassifier — single fused split-bf16 MFMA kernel.
// out[n,k] = -(2*atanh(clamp(z)))^2, z = ||mobius_add(-x_n,p_k)|| (c=1).
// ||num||^2 = a^2*x2 - 2ab*xy + b^2*p2 -> only x2, p2, xy needed.
// xy via MFMA, exact hi/lo bf16 split: xy ~= xh*ph + xh*pl + xl*ph.
//
// Structure (round-7): no LDS, no barriers, no workspace. 1024 blocks x 256
// (4 blocks/CU = 4 waves/SIMD). Block = 16 n-rows x 128 k; wave w owns
// k-tiles 2w,2w+1. Each lane builds A/B fragments straight from global
// (x: 4 MB cold, coalesced within quad-groups; p: 32 KB L2/L1-hot) and
// converts inline. Row norms via 2x shfl_xor over the m16-quad; projection
// scale is per-output-column = per-lane (no redistribution); x2 for the 4
// C-rows via 4 bpermutes. Layout validated in R4 (absmax 0.03125):
// A/B lane(q=lane>>4,m16): row m16, d-chunks q*8 and 32+q*8; C/D row=q*4+r, col=m16.

typedef __attribute__((ext_vector_type(8))) short bf16x8;
typedef __attribute__((ext_vector_type(4))) float f32x4;

#define K_PROTO 128

union u4bf8 { uint4 u; bf16x8 b; };

__device__ __forceinline__ unsigned pack_hi(float a, float b, float* ra, float* rb) {
    unsigned ua = __float_as_uint(a), ub = __float_as_uint(b);
    unsigned ha = (ua + 0x7fffu + ((ua >> 16) & 1u)) >> 16;   // RNE bf16
    unsigned hb = (ub + 0x7fffu + ((ub >> 16) & 1u)) >> 16;
    *ra = a - __uint_as_float(ha << 16);                      // exact residual
    *rb = b - __uint_as_float(hb << 16);
    return ha | (hb << 16);
}
__device__ __forceinline__ unsigned pack_bf(float a, float b) {
    unsigned ua = __float_as_uint(a), ub = __float_as_uint(b);
    unsigned ha = (ua + 0x7fffu + ((ua >> 16) & 1u)) >> 16;
    unsigned hb = (ub + 0x7fffu + ((ub >> 16) & 1u)) >> 16;
    return ha | (hb << 16);
}
__device__ __forceinline__ void cvt8(float4 v0, float4 v1, bf16x8* h, bf16x8* l) {
    float r[8];
    u4bf8 hv, lv;
    hv.u.x = pack_hi(v0.x, v0.y, &r[0], &r[1]);
    hv.u.y = pack_hi(v0.z, v0.w, &r[2], &r[3]);
    hv.u.z = pack_hi(v1.x, v1.y, &r[4], &r[5]);
    hv.u.w = pack_hi(v1.z, v1.w, &r[6], &r[7]);
    lv.u.x = pack_bf(r[0], r[1]);
    lv.u.y = pack_bf(r[2], r[3]);
    lv.u.z = pack_bf(r[4], r[5]);
    lv.u.w = pack_bf(r[6], r[7]);
    *h = hv.b;
    *l = lv.b;
}
__device__ __forceinline__ float dot4(float4 v) {
    return v.x * v.x + v.y * v.y + v.z * v.z + v.w * v.w;
}

__global__ __launch_bounds__(256, 4) void geodesic_fused(
    const float* __restrict__ x,
    const float* __restrict__ p,
    float* __restrict__ out)
{
    const int t    = threadIdx.x;
    const int g    = blockIdx.x;       // n-rows g*16 .. g*16+15
    const int w    = t >> 6;           // wave -> k-tiles 2w, 2w+1
    const int lane = t & 63;
    const int m16  = lane & 15;
    const int q    = lane >> 4;

    // ---- A fragment: row g*16+m16, d-chunks [q*8,+8) and [32+q*8,+8) ----
    const float* xr = x + (size_t)(g * 16 + m16) * 64 + q * 8;
    float4 a0 = *(const float4*)(xr);
    float4 a1 = *(const float4*)(xr + 4);
    float4 b0 = *(const float4*)(xr + 32);
    float4 b1 = *(const float4*)(xr + 36);

    // full-row ||x||^2 via m16-quad reduce (lanes m16+16q)
    float sx = dot4(a0) + dot4(a1) + dot4(b0) + dot4(b1);
    sx += __shfl_xor(sx, 16);
    sx += __shfl_xor(sx, 32);

    bf16x8 xh0, xl0, xh1, xl1;
    cvt8(a0, a1, &xh0, &xl0);
    cvt8(b0, b1, &xh1, &xl1);

    // x2 for this lane's 4 C-rows (q*4+r): held by lanes q*4+r
    float x2v[4];
    #pragma unroll
    for (int r = 0; r < 4; ++r) x2v[r] = __shfl(sx, q * 4 + r);

    // ---- two k-tiles per wave ----
    #pragma unroll
    for (int kk = 0; kk < 2; ++kk) {
        const int kt = 2 * w + kk;
        const float* pr = p + (size_t)(kt * 16 + m16) * 64 + q * 8;
        float4 c0 = *(const float4*)(pr);
        float4 c1 = *(const float4*)(pr + 4);
        float4 d0 = *(const float4*)(pr + 32);
        float4 d1 = *(const float4*)(pr + 36);

        float sp = dot4(c0) + dot4(c1) + dot4(d0) + dot4(d1);
        sp += __shfl_xor(sp, 16);
        sp += __shfl_xor(sp, 32);                 // raw ||p_row||^2
        float nrm = fmaxf(sqrtf(sp), 1e-15f);
        float sc  = fminf(1.0f, 0.999f / nrm);    // (1-BALL_EPS)/sqrt(c)
        float p2  = sp * sc * sc;                 // ||p_proj||^2

        bf16x8 ph0, pl0, ph1, pl1;
        cvt8(c0, c1, &ph0, &pl0);
        cvt8(d0, d1, &ph1, &pl1);

        f32x4 acc = {0.f, 0.f, 0.f, 0.f};
        acc = __builtin_amdgcn_mfma_f32_16x16x32_bf16(xh0, ph0, acc, 0, 0, 0);
        acc = __builtin_amdgcn_mfma_f32_16x16x32_bf16(xh1, ph1, acc, 0, 0, 0);
        acc = __builtin_amdgcn_mfma_f32_16x16x32_bf16(xh0, pl0, acc, 0, 0, 0);
        acc = __builtin_amdgcn_mfma_f32_16x16x32_bf16(xh1, pl1, acc, 0, 0, 0);
        acc = __builtin_amdgcn_mfma_f32_16x16x32_bf16(xl0, ph0, acc, 0, 0, 0);
        acc = __builtin_amdgcn_mfma_f32_16x16x32_bf16(xl1, ph1, acc, 0, 0, 0);

        // ---- epilogue: 4 outputs, col = kt*16+m16 (this lane's p-row) ----
        #pragma unroll
        for (int r = 0; r < 4; ++r) {
            const float x2  = x2v[r];
            const float xy  = acc[r] * sc;        // fold projection scale
            const float aa  = 1.0f - 2.0f * xy + p2;
            const float bb  = 1.0f - x2;
            const float den = fmaxf(1.0f - 2.0f * xy + x2 * p2, 1e-15f);
            const float n2  = fmaxf(aa * aa * x2 - 2.0f * aa * bb * xy + bb * bb * p2, 0.0f);
            const float sv  = fminf(sqrtf(n2), 0.99999f * den);   // z=sv/den<=1-1e-5
            const float lg  = __logf(__fdividef(den + sv, den - sv));
            out[(size_t)(g * 16 + q * 4 + r) * K_PROTO + kt * 16 + m16] = -(lg * lg);
        }
    }
}

extern "C" void kernel_launch(void* const* d_in, const int* in_sizes, int n_in,
                              void* d_out, int out_size, void* d_ws, size_t ws_size,
                              hipStream_t stream) {
    const float* x = (const float*)d_in[0];   // (16384, 64) f32
    const float* p = (const float*)d_in[1];   // (128, 64) f32
    float* out = (float*)d_out;               // (16384, 128) f32

    hipLaunchKernelGGL(geodesic_fused, dim3(1024), dim3(256), 0, stream, x, p, out);
}